// Round 12
// baseline (641.004 us; speedup 1.0000x reference)
//
#include <hip/hip_runtime.h>
#include <hip/hip_fp16.h>
#include <math.h>

constexpr int PAD = 0;
constexpr int Lc = 128;   // sequence length
constexpr int Dc = 128;   // embedding dim
constexpr int NSLICE = 4; // vocab slices (XCD k caches slice k%4 under round-robin)
constexpr float MIN_NORM = 1e-15f;
constexpr float CLAMP_ABS_EPS = 1e-10f;
constexpr float ATANH_EPS = 1e-7f;

__device__ __forceinline__ float red64(float v) {
    v += __shfl_xor(v, 32);
    v += __shfl_xor(v, 16);
    v += __shfl_xor(v, 8);
    v += __shfl_xor(v, 4);
    v += __shfl_xor(v, 2);
    v += __shfl_xor(v, 1);
    return v;
}

__device__ __forceinline__ __half2 h2xadd(__half2 a, int m) {
    unsigned u = *reinterpret_cast<unsigned*>(&a);
    unsigned t = __shfl_xor(u, m);
    return __hadd2(a, *reinterpret_cast<__half2*>(&t));
}

// ==== kernel 1: prep (table pass) + bucket (idx pass) fused; independent block ranges ====
__global__ __launch_bounds__(256) void prep_bucket_kernel(
        const float* __restrict__ emb,
        const int* __restrict__ padded,
        __half* __restrict__ w16,            // [(V+1)][128], row V = zeros
        float* __restrict__ lam,             // [V+1], lam[V] = 0
        unsigned short* __restrict__ cidx,   // [Bn][128] slice-sorted token ids
        unsigned short* __restrict__ offs,   // [Bn][5] slice offsets, [4]=total cnt
        int* __restrict__ ctr,               // [nGrp] completion counters
        int nPrep, int V, int Bn, int V4, int nGrp) {
    const int blk  = blockIdx.x;
    const int tid  = threadIdx.x;
    const int lane = tid & 63;

    if (blk < nPrep) {
        // ---- prep: 4 table rows per block ----
        if (blk == 0) {  // zero the completion counters for this launch
            for (int i = tid; i < nGrp; i += 256) ctr[i] = 0;
        }
        const int row = blk * 4 + (tid >> 6);
        if (row > V) return;
        if (row == V) {  // dummy zero row + lam[V]=0 (pad slots become free)
            if (lane == 0) lam[V] = 0.f;
            *reinterpret_cast<__half2*>(w16 + (size_t)V * Dc + lane * 2) =
                __floats2half2_rn(0.f, 0.f);
            return;
        }
        const float2 z = *reinterpret_cast<const float2*>(emb + (size_t)row * Dc + lane * 2);
        const float p = red64(z.x * z.x + z.y * z.y);
        const float lamv = 2.0f / fmaxf(1.0f - p, MIN_NORM);
        if (lane == 0) lam[row] = lamv;
        *reinterpret_cast<__half2*>(w16 + (size_t)row * Dc + lane * 2) =
            __floats2half2_rn(lamv * z.x, lamv * z.y);
    } else {
        // ---- bucket: 4 batch rows per block (needs only padded, not lam) ----
        const int row = (blk - nPrep) * 4 + (tid >> 6);
        if (row >= Bn) return;
        const int i0 = padded[(size_t)row * Lc + lane];
        const int i1 = padded[(size_t)row * Lc + 64 + lane];
        const bool p0 = (i0 != PAD);
        const bool p1 = (i1 != PAD);
        const int s0 = (i0 >= V4) + (i0 >= 2 * V4) + (i0 >= 3 * V4);
        const int s1 = (i1 >= V4) + (i1 >= 2 * V4) + (i1 >= 3 * V4);
        const unsigned long long lmask = (1ull << lane) - 1ull;
        int running = 0;
        #pragma unroll
        for (int s = 0; s < NSLICE; ++s) {
            const unsigned long long m0 = __ballot(p0 && (s0 == s));
            const unsigned long long m1 = __ballot(p1 && (s1 == s));
            const int c0 = __popcll(m0);
            if (lane == 0) offs[(size_t)row * 5 + s] = (unsigned short)running;
            if (p0 && (s0 == s))
                cidx[(size_t)row * Lc + running + __popcll(m0 & lmask)] = (unsigned short)i0;
            if (p1 && (s1 == s))
                cidx[(size_t)row * Lc + running + c0 + __popcll(m1 & lmask)] = (unsigned short)i1;
            running += c0 + __popcll(m1);
        }
        if (lane == 0) offs[(size_t)row * 5 + 4] = (unsigned short)running;
    }
}

// ==== kernel 2: slice-local gather + last-block final (norm chain + output) ====
__global__ __launch_bounds__(256) void gather_final_kernel(
        const unsigned short* __restrict__ cidx,
        const unsigned short* __restrict__ offs,
        const float* __restrict__ lam,
        const __half* __restrict__ w16,
        uint2* __restrict__ pnum,      // [Bn*4][32] packed half2x2 (128 dims)
        float* __restrict__ pmeta,     // [Bn*4] per-slice sum(lam)
        int* __restrict__ ctr,         // [nGrp]
        float* __restrict__ out,
        int Bn, int V) {
    const int sl   = blockIdx.x & (NSLICE - 1);  // round-robin -> stable XCD per slice
    const int grp  = blockIdx.x >> 2;
    const int r0   = grp * 8;
    const int tid  = threadIdx.x;
    const int w    = tid >> 6;
    const int lane = tid & 63;
    const int q    = lane >> 4;
    const int l16  = lane & 15;

    __shared__ int sidx[4][2][Lc + 16];
    __shared__ int s_last;

    #pragma unroll
    for (int rr = 0; rr < 2; ++rr) {
        const int row = r0 + w * 2 + rr;
        if (row >= Bn) continue;
        const int off = offs[(size_t)row * 5 + sl];
        const int nxt = offs[(size_t)row * 5 + sl + 1];
        const int cnt = nxt - off;
        // stage slots; out-of-range -> dummy row V (w16 zeros, lam 0)
        {
            const int s0i = off + lane;
            const int s1i = off + 64 + lane;
            const int t0 = (int)cidx[(size_t)row * Lc + (s0i < Lc ? s0i : Lc - 1)];
            const int t1 = (int)cidx[(size_t)row * Lc + (s1i < Lc ? s1i : Lc - 1)];
            sidx[w][rr][lane]      = (lane      < cnt) ? t0 : V;
            sidx[w][rr][64 + lane] = (64 + lane < cnt) ? t1 : V;
            if (lane < 16) sidx[w][rr][Lc + lane] = V;
        }
        // per-slice sum(lam): 200KB lam array is L2-resident; dummy slots read 0
        const float sls = red64(lam[sidx[w][rr][lane]] + lam[sidx[w][rr][64 + lane]]);

        const __half2 hz = __floats2half2_rn(0.f, 0.f);
        __half2 a0 = hz, a1 = hz, a2 = hz, a3 = hz;
        __half2 b0 = hz, b1 = hz, b2 = hz, b3 = hz;
        for (int k = q; k < cnt; k += 16) {
            const int i0 = sidx[w][rr][k];
            const int i1 = sidx[w][rr][k + 4];
            const int i2 = sidx[w][rr][k + 8];
            const int i3 = sidx[w][rr][k + 12];
            const uint4 v0 = *reinterpret_cast<const uint4*>(w16 + ((size_t)i0 << 7) + (l16 << 3));
            const uint4 v1 = *reinterpret_cast<const uint4*>(w16 + ((size_t)i1 << 7) + (l16 << 3));
            const uint4 v2 = *reinterpret_cast<const uint4*>(w16 + ((size_t)i2 << 7) + (l16 << 3));
            const uint4 v3 = *reinterpret_cast<const uint4*>(w16 + ((size_t)i3 << 7) + (l16 << 3));
            a0 = __hadd2(a0, *reinterpret_cast<const __half2*>(&v0.x));
            a1 = __hadd2(a1, *reinterpret_cast<const __half2*>(&v0.y));
            a2 = __hadd2(a2, *reinterpret_cast<const __half2*>(&v0.z));
            a3 = __hadd2(a3, *reinterpret_cast<const __half2*>(&v0.w));
            b0 = __hadd2(b0, *reinterpret_cast<const __half2*>(&v1.x));
            b1 = __hadd2(b1, *reinterpret_cast<const __half2*>(&v1.y));
            b2 = __hadd2(b2, *reinterpret_cast<const __half2*>(&v1.z));
            b3 = __hadd2(b3, *reinterpret_cast<const __half2*>(&v1.w));
            a0 = __hadd2(a0, *reinterpret_cast<const __half2*>(&v2.x));
            a1 = __hadd2(a1, *reinterpret_cast<const __half2*>(&v2.y));
            a2 = __hadd2(a2, *reinterpret_cast<const __half2*>(&v2.z));
            a3 = __hadd2(a3, *reinterpret_cast<const __half2*>(&v2.w));
            b0 = __hadd2(b0, *reinterpret_cast<const __half2*>(&v3.x));
            b1 = __hadd2(b1, *reinterpret_cast<const __half2*>(&v3.y));
            b2 = __hadd2(b2, *reinterpret_cast<const __half2*>(&v3.z));
            b3 = __hadd2(b3, *reinterpret_cast<const __half2*>(&v3.w));
        }
        a0 = __hadd2(a0, b0); a1 = __hadd2(a1, b1);
        a2 = __hadd2(a2, b2); a3 = __hadd2(a3, b3);
        a0 = h2xadd(a0, 16); a1 = h2xadd(a1, 16); a2 = h2xadd(a2, 16); a3 = h2xadd(a3, 16);
        a0 = h2xadd(a0, 32); a1 = h2xadd(a1, 32); a2 = h2xadd(a2, 32); a3 = h2xadd(a3, 32);
        if (lane < 16) {
            uint4 u;
            u.x = *reinterpret_cast<unsigned*>(&a0);
            u.y = *reinterpret_cast<unsigned*>(&a1);
            u.z = *reinterpret_cast<unsigned*>(&a2);
            u.w = *reinterpret_cast<unsigned*>(&a3);
            *reinterpret_cast<uint4*>(
                &pnum[((size_t)row * NSLICE + sl) * 32 + (l16 << 1)]) = u;
        }
        if (lane == 0) pmeta[(size_t)row * NSLICE + sl] = sls;
    }

    // ---- last-block-done: 4th slice-block of this row-group runs the finale ----
    __threadfence();          // release this block's pnum/pmeta stores
    __syncthreads();
    if (tid == 0) s_last = (atomicAdd(&ctr[grp], 1) == NSLICE - 1);
    __syncthreads();
    if (!s_last) return;
    __threadfence();          // acquire other blocks' stores

    const int h = lane >> 5;
    const int p = lane & 31;
    #pragma unroll
    for (int rr = 0; rr < 2; ++rr) {
        const int row = r0 + w * 2 + rr;
        if (row >= Bn) continue;
        const int cnt = (int)offs[(size_t)row * 5 + 4];
        float* orow = out + (size_t)row * (4 * Dc);
        if (cnt == 0) {
            if (lane < 32) {
                const float4 z4 = make_float4(0.f, 0.f, 0.f, 0.f);
                #pragma unroll
                for (int sc = 0; sc < 4; ++sc)
                    *reinterpret_cast<float4*>(orow + sc * Dc + 4 * p) = z4;
            }
            continue;
        }
        const float slam = pmeta[(size_t)row * NSLICE + 0] + pmeta[(size_t)row * NSLICE + 1]
                         + pmeta[(size_t)row * NSLICE + 2] + pmeta[(size_t)row * NSLICE + 3];
        float4 v = make_float4(0.f, 0.f, 0.f, 0.f);
        #pragma unroll
        for (int j = 0; j < 2; ++j) {
            const int s = h * 2 + j;
            const uint2 u = pnum[((size_t)row * NSLICE + s) * 32 + p];
            const float2 f0 = __half22float2(*reinterpret_cast<const __half2*>(&u.x));
            const float2 f1 = __half22float2(*reinterpret_cast<const __half2*>(&u.y));
            v.x += f0.x; v.y += f0.y; v.z += f1.x; v.w += f1.y;
        }
        v.x += __shfl_xor(v.x, 32);
        v.y += __shfl_xor(v.y, 32);
        v.z += __shfl_xor(v.z, 32);
        v.w += __shfl_xor(v.w, 32);

        const float cntf  = (float)cnt;
        const float rc    = 1.0f / cntf;
        const float dn    = (slam - cntf) * rc;             // mean(lam-1)
        const float denom = ((dn >= 0.f) ? 1.0f : -1.0f) * fmaxf(fabsf(dn), CLAMP_ABS_EPS);
        const float s1    = rc / denom;
        const float4 tm = make_float4(v.x * s1, v.y * s1, v.z * s1, v.w * s1);

        const float p2 = (lane < 32) ? (tm.x*tm.x + tm.y*tm.y + tm.z*tm.z + tm.w*tm.w) : 0.f;
        const float n2 = fmaxf(sqrtf(red64(p2)), MIN_NORM);
        const float xc = fminf(n2, 1.0f - ATANH_EPS);
        const float th = xc / (1.0f + sqrtf(fmaxf(1.0f - xc * xc, 0.f)));  // tanh(0.5*artanh)
        const float k1 = th / n2;
        const float4 mid = make_float4(tm.x * k1, tm.y * k1, tm.z * k1, tm.w * k1);

        const float q2 = (lane < 32) ? (mid.x*mid.x + mid.y*mid.y + mid.z*mid.z + mid.w*mid.w) : 0.f;
        const float nm  = fmaxf(sqrtf(red64(q2)), MIN_NORM);
        const float xc2 = fminf(nm, 1.0f - ATANH_EPS);
        const float f   = 0.5f * logf((1.0f + xc2) / (1.0f - xc2));        // artanh
        const float k2  = f / nm;

        if (lane < 32) {
            const float4 o = make_float4(mid.x * k2, mid.y * k2, mid.z * k2, mid.w * k2);
            #pragma unroll
            for (int sc = 0; sc < 4; ++sc)
                *reinterpret_cast<float4*>(orow + sc * Dc + 4 * p) = o;
        }
    }
}

// ---- fallback (small ws): prep + single-kernel gather over w16 table ----
__global__ __launch_bounds__(256) void prep_kernel(
        const float* __restrict__ emb,
        __half* __restrict__ w16,
        float* __restrict__ lam, int V) {
    const int row  = blockIdx.x * 4 + (threadIdx.x >> 6);
    const int lane = threadIdx.x & 63;
    if (row >= V) return;
    const float2 z = *reinterpret_cast<const float2*>(emb + (size_t)row * Dc + lane * 2);
    const float p = red64(z.x * z.x + z.y * z.y);
    const float lamv = 2.0f / fmaxf(1.0f - p, MIN_NORM);
    if (lane == 0) lam[row] = lamv;
    *reinterpret_cast<__half2*>(w16 + (size_t)row * Dc + lane * 2) =
        __floats2half2_rn(lamv * z.x, lamv * z.y);
}

__global__ __launch_bounds__(256) void hyper_enc_kernel(
        const int* __restrict__ padded,
        const __half* __restrict__ w16,
        const float* __restrict__ lam,
        float* __restrict__ out) {
    const int b    = blockIdx.x;
    const int tid  = threadIdx.x;
    const int wave = tid >> 6;
    const int lane = tid & 63;
    const int half = lane >> 5;
    const int l32  = lane & 31;

    __shared__ int   sidx[Lc];
    __shared__ float s_num[8][Dc];
    __shared__ int   s_cnt;
    __shared__ float s_den[2];
    __shared__ float s_red[4];

    int   myidx = 0;
    float mylam = 0.f;
    if (tid < Lc) {
        myidx = padded[(size_t)b * Lc + tid];
        sidx[tid] = myidx;
        mylam = (myidx != PAD) ? lam[myidx] : 0.0f;
    }
    if (tid == 0) s_cnt = 0;
    __syncthreads();
    if (tid < Lc) {
        unsigned long long bal = __ballot(myidx != PAD);
        if (lane == 0) atomicAdd(&s_cnt, (int)__popcll(bal));
        float sl = red64(mylam);
        if (lane == 0) s_den[wave] = sl;
    }

    float4 snum = make_float4(0.f, 0.f, 0.f, 0.f);
    const int lbase = wave * 32 + half;
    __syncthreads();
    #pragma unroll
    for (int j = 0; j < 16; ++j) {
        const int idx = sidx[lbase + 2 * j];
        const uint2 r = *reinterpret_cast<const uint2*>(
            w16 + ((size_t)idx << 7) + (l32 << 2));
        const float2 f0 = __half22float2(*reinterpret_cast<const __half2*>(&r.x));
        const float2 f1 = __half22float2(*reinterpret_cast<const __half2*>(&r.y));
        snum.x += f0.x; snum.y += f0.y; snum.z += f1.x; snum.w += f1.y;
    }
    const int g = wave * 2 + half;
    *reinterpret_cast<float4*>(&s_num[g][l32 * 4]) = snum;
    __syncthreads();

    const int cnt = s_cnt;
    if (cnt == 0) {
        for (int i = tid; i < 4 * Dc; i += 256)
            out[(size_t)b * (4 * Dc) + i] = 0.f;
        return;
    }
    const float Sd = (s_den[0] + s_den[1]) - (float)cnt;

    float nom = 0.f;
    if (tid < Dc) {
        #pragma unroll
        for (int gg = 0; gg < 8; ++gg) nom += s_num[gg][tid];
    }
    float tm = 0.f;
    if (tid < Dc) {
        const float rc    = 1.0f / (float)cnt;
        const float dn    = Sd * rc;
        const float denom = ((dn >= 0.f) ? 1.0f : -1.0f) * fmaxf(fabsf(dn), CLAMP_ABS_EPS);
        tm = (nom * rc) / denom;
    }
    float p2 = red64(tm * tm);
    if (lane == 0) s_red[wave] = p2;
    __syncthreads();
    const float n2 = fmaxf(sqrtf(s_red[0] + s_red[1]), MIN_NORM);
    const float xc = fminf(n2, 1.0f - ATANH_EPS);
    const float t_half = xc / (1.0f + sqrtf(fmaxf(1.0f - xc * xc, 0.f)));
    const float mid = tm * (t_half / n2);
    __syncthreads();
    float q2 = red64(mid * mid);
    if (lane == 0) s_red[wave] = q2;
    __syncthreads();
    const float nm  = fmaxf(sqrtf(s_red[0] + s_red[1]), MIN_NORM);
    const float xc2 = fminf(nm, 1.0f - ATANH_EPS);
    const float f   = 0.5f * logf((1.0f + xc2) / (1.0f - xc2));
    if (tid < Dc) {
        const float o = mid * (f / nm);
        float* orow = out + (size_t)b * (4 * Dc);
        orow[0 * Dc + tid] = o;
        orow[1 * Dc + tid] = o;
        orow[2 * Dc + tid] = o;
        orow[3 * Dc + tid] = o;
    }
}

static inline size_t align256(size_t x) { return (x + 255) & ~(size_t)255; }

extern "C" void kernel_launch(void* const* d_in, const int* in_sizes, int n_in,
                              void* d_out, int out_size, void* d_ws, size_t ws_size,
                              hipStream_t stream) {
    const int*   padded = (const int*)d_in[0];
    const float* emb    = (const float*)d_in[1];
    float*       out    = (float*)d_out;
    const int Bn = in_sizes[0] / Lc;             // 8192
    const int V  = in_sizes[1] / Dc;             // 50000
    const int V4 = (V + NSLICE - 1) / NSLICE;
    const int nGrp = (Bn + 7) / 8;

    const size_t w16_b   = align256((size_t)(V + 1) * Dc * sizeof(__half));      // 12.8 MB
    const size_t lam_b   = align256((size_t)(V + 1) * sizeof(float));            // 200 KB
    const size_t cidx_b  = align256((size_t)Bn * Lc * sizeof(unsigned short));   // 2 MB
    const size_t offs_b  = align256((size_t)Bn * 5 * sizeof(unsigned short));
    const size_t pmeta_b = align256((size_t)Bn * NSLICE * sizeof(float));
    const size_t pnum_b  = align256((size_t)Bn * NSLICE * 32 * sizeof(uint2));   // 8.4 MB
    const size_t ctr_b   = align256((size_t)nGrp * sizeof(int));
    const size_t need    = w16_b + lam_b + cidx_b + offs_b + pmeta_b + pnum_b + ctr_b;

    if (ws_size >= need) {
        char* p = (char*)d_ws;
        __half*         w16   = (__half*)p;          p += w16_b;
        float*          lam   = (float*)p;           p += lam_b;
        unsigned short* cidx  = (unsigned short*)p;  p += cidx_b;
        unsigned short* offs  = (unsigned short*)p;  p += offs_b;
        float*          pmeta = (float*)p;           p += pmeta_b;
        uint2*          pnum  = (uint2*)p;           p += pnum_b;
        int*            ctr   = (int*)p;
        const int nPrep   = (V + 1 + 3) / 4;
        const int nBucket = (Bn + 3) / 4;
        prep_bucket_kernel<<<nPrep + nBucket, 256, 0, stream>>>(
            emb, padded, w16, lam, cidx, offs, ctr, nPrep, V, Bn, V4, nGrp);
        gather_final_kernel<<<NSLICE * nGrp, 256, 0, stream>>>(
            cidx, offs, lam, w16, pnum, pmeta, ctr, out, Bn, V);
    } else if (ws_size >= w16_b + lam_b) {
        __half* w16 = (__half*)d_ws;
        float*  lam = (float*)((char*)d_ws + w16_b);
        prep_kernel<<<(V + 3) / 4, 256, 0, stream>>>(emb, w16, lam, V);
        hyper_enc_kernel<<<Bn, 256, 0, stream>>>(padded, w16, lam, out);
    }
}

// Round 13
// 43.349 us; speedup vs baseline: 14.7871x; 14.7871x over previous
//
#include <hip/hip_runtime.h>
#include <hip/hip_fp16.h>
#include <math.h>

constexpr int PAD = 0;
constexpr int Lc = 128;   // sequence length
constexpr int Dc = 128;   // embedding dim
constexpr int NSLICE = 4; // vocab slices (XCD k caches slice k%4 under round-robin)
constexpr float MIN_NORM = 1e-15f;
constexpr float CLAMP_ABS_EPS = 1e-10f;
constexpr float ATANH_EPS = 1e-7f;

__device__ __forceinline__ float red64(float v) {
    v += __shfl_xor(v, 32);
    v += __shfl_xor(v, 16);
    v += __shfl_xor(v, 8);
    v += __shfl_xor(v, 4);
    v += __shfl_xor(v, 2);
    v += __shfl_xor(v, 1);
    return v;
}

__device__ __forceinline__ __half2 h2xadd(__half2 a, int m) {
    unsigned u = *reinterpret_cast<unsigned*>(&a);
    unsigned t = __shfl_xor(u, m);
    return __hadd2(a, *reinterpret_cast<__half2*>(&t));
}

// ==== kernel 1: prep (table) + bucket (indices) fused via disjoint block ranges ====
__global__ __launch_bounds__(256) void prep_bucket_kernel(
        const float* __restrict__ emb,
        const int* __restrict__ padded,
        __half* __restrict__ w16,            // [(V+1)][128], row V = zeros
        float* __restrict__ lam,             // [V+1], lam[V] = 0
        unsigned short* __restrict__ cidx,   // [Bn][128] slice-sorted token ids
        unsigned short* __restrict__ offs,   // [Bn][5] slice offsets, [4]=total cnt
        int nPrep, int V, int Bn, int V4) {
    const int blk  = blockIdx.x;
    const int tid  = threadIdx.x;
    const int lane = tid & 63;

    if (blk < nPrep) {
        // ---- prep: 4 table rows per block ----
        const int row = blk * 4 + (tid >> 6);
        if (row > V) return;
        if (row == V) {  // dummy zero row + lam[V]=0 (pad slots become free)
            if (lane == 0) lam[V] = 0.f;
            *reinterpret_cast<__half2*>(w16 + (size_t)V * Dc + lane * 2) =
                __floats2half2_rn(0.f, 0.f);
            return;
        }
        const float2 z = *reinterpret_cast<const float2*>(emb + (size_t)row * Dc + lane * 2);
        const float p = red64(z.x * z.x + z.y * z.y);
        const float lamv = 2.0f / fmaxf(1.0f - p, MIN_NORM);
        if (lane == 0) lam[row] = lamv;
        *reinterpret_cast<__half2*>(w16 + (size_t)row * Dc + lane * 2) =
            __floats2half2_rn(lamv * z.x, lamv * z.y);
    } else {
        // ---- bucket: 4 batch rows per block (independent of prep's outputs) ----
        const int row = (blk - nPrep) * 4 + (tid >> 6);
        if (row >= Bn) return;
        const int i0 = padded[(size_t)row * Lc + lane];
        const int i1 = padded[(size_t)row * Lc + 64 + lane];
        const bool p0 = (i0 != PAD);
        const bool p1 = (i1 != PAD);
        const int s0 = (i0 >= V4) + (i0 >= 2 * V4) + (i0 >= 3 * V4);
        const int s1 = (i1 >= V4) + (i1 >= 2 * V4) + (i1 >= 3 * V4);
        const unsigned long long lmask = (1ull << lane) - 1ull;
        int running = 0;
        #pragma unroll
        for (int s = 0; s < NSLICE; ++s) {
            const unsigned long long m0 = __ballot(p0 && (s0 == s));
            const unsigned long long m1 = __ballot(p1 && (s1 == s));
            const int c0 = __popcll(m0);
            if (lane == 0) offs[(size_t)row * 5 + s] = (unsigned short)running;
            if (p0 && (s0 == s))
                cidx[(size_t)row * Lc + running + __popcll(m0 & lmask)] = (unsigned short)i0;
            if (p1 && (s1 == s))
                cidx[(size_t)row * Lc + running + c0 + __popcll(m1 & lmask)] = (unsigned short)i1;
            running += c0 + __popcll(m1);
        }
        if (lane == 0) offs[(size_t)row * 5 + 4] = (unsigned short)running;
    }
}

// ==== kernel 2: slice-local gather-add; 16 tokens in flight; branch-free via dummy row ====
__global__ __launch_bounds__(256) void partial_kernel(
        const unsigned short* __restrict__ cidx,
        const unsigned short* __restrict__ offs,
        const float* __restrict__ lam,
        const __half* __restrict__ w16,
        uint2* __restrict__ pnum,      // [Bn*4][32] packed half2x2 (128 dims)
        float* __restrict__ pmeta,     // [Bn*4] per-slice sum(lam)
        int Bn, int V) {
    const int sl   = blockIdx.x & (NSLICE - 1);  // round-robin -> stable XCD per slice
    const int r0   = (blockIdx.x >> 2) * 8;
    const int tid  = threadIdx.x;
    const int w    = tid >> 6;
    const int lane = tid & 63;
    const int q    = lane >> 4;
    const int l16  = lane & 15;

    __shared__ int sidx[4][2][Lc + 16];

    #pragma unroll
    for (int rr = 0; rr < 2; ++rr) {
        const int row = r0 + w * 2 + rr;
        if (row >= Bn) continue;
        const int off = offs[(size_t)row * 5 + sl];
        const int nxt = offs[(size_t)row * 5 + sl + 1];
        const int cnt = nxt - off;
        // stage slots; out-of-range -> dummy row V (w16 zeros, lam 0)
        {
            const int s0i = off + lane;
            const int s1i = off + 64 + lane;
            const int t0 = (int)cidx[(size_t)row * Lc + (s0i < Lc ? s0i : Lc - 1)];
            const int t1 = (int)cidx[(size_t)row * Lc + (s1i < Lc ? s1i : Lc - 1)];
            sidx[w][rr][lane]      = (lane      < cnt) ? t0 : V;
            sidx[w][rr][64 + lane] = (64 + lane < cnt) ? t1 : V;
            if (lane < 16) sidx[w][rr][Lc + lane] = V;
        }
        // per-slice sum(lam): 200KB lam array is L2-resident; dummy slots read 0
        const float sls = red64(lam[sidx[w][rr][lane]] + lam[sidx[w][rr][64 + lane]]);

        const __half2 hz = __floats2half2_rn(0.f, 0.f);
        __half2 a0 = hz, a1 = hz, a2 = hz, a3 = hz;
        __half2 b0 = hz, b1 = hz, b2 = hz, b3 = hz;
        for (int k = q; k < cnt; k += 16) {
            const int i0 = sidx[w][rr][k];
            const int i1 = sidx[w][rr][k + 4];
            const int i2 = sidx[w][rr][k + 8];
            const int i3 = sidx[w][rr][k + 12];
            const uint4 v0 = *reinterpret_cast<const uint4*>(w16 + ((size_t)i0 << 7) + (l16 << 3));
            const uint4 v1 = *reinterpret_cast<const uint4*>(w16 + ((size_t)i1 << 7) + (l16 << 3));
            const uint4 v2 = *reinterpret_cast<const uint4*>(w16 + ((size_t)i2 << 7) + (l16 << 3));
            const uint4 v3 = *reinterpret_cast<const uint4*>(w16 + ((size_t)i3 << 7) + (l16 << 3));
            a0 = __hadd2(a0, *reinterpret_cast<const __half2*>(&v0.x));
            a1 = __hadd2(a1, *reinterpret_cast<const __half2*>(&v0.y));
            a2 = __hadd2(a2, *reinterpret_cast<const __half2*>(&v0.z));
            a3 = __hadd2(a3, *reinterpret_cast<const __half2*>(&v0.w));
            b0 = __hadd2(b0, *reinterpret_cast<const __half2*>(&v1.x));
            b1 = __hadd2(b1, *reinterpret_cast<const __half2*>(&v1.y));
            b2 = __hadd2(b2, *reinterpret_cast<const __half2*>(&v1.z));
            b3 = __hadd2(b3, *reinterpret_cast<const __half2*>(&v1.w));
            a0 = __hadd2(a0, *reinterpret_cast<const __half2*>(&v2.x));
            a1 = __hadd2(a1, *reinterpret_cast<const __half2*>(&v2.y));
            a2 = __hadd2(a2, *reinterpret_cast<const __half2*>(&v2.z));
            a3 = __hadd2(a3, *reinterpret_cast<const __half2*>(&v2.w));
            b0 = __hadd2(b0, *reinterpret_cast<const __half2*>(&v3.x));
            b1 = __hadd2(b1, *reinterpret_cast<const __half2*>(&v3.y));
            b2 = __hadd2(b2, *reinterpret_cast<const __half2*>(&v3.z));
            b3 = __hadd2(b3, *reinterpret_cast<const __half2*>(&v3.w));
        }
        a0 = __hadd2(a0, b0); a1 = __hadd2(a1, b1);
        a2 = __hadd2(a2, b2); a3 = __hadd2(a3, b3);
        // combine the 4 quarters (same dims, different tokens)
        a0 = h2xadd(a0, 16); a1 = h2xadd(a1, 16); a2 = h2xadd(a2, 16); a3 = h2xadd(a3, 16);
        a0 = h2xadd(a0, 32); a1 = h2xadd(a1, 32); a2 = h2xadd(a2, 32); a3 = h2xadd(a3, 32);
        if (lane < 16) {
            uint4 u;
            u.x = *reinterpret_cast<unsigned*>(&a0);
            u.y = *reinterpret_cast<unsigned*>(&a1);
            u.z = *reinterpret_cast<unsigned*>(&a2);
            u.w = *reinterpret_cast<unsigned*>(&a3);
            *reinterpret_cast<uint4*>(
                &pnum[((size_t)row * NSLICE + sl) * 32 + (l16 << 1)]) = u;
        }
        if (lane == 0) pmeta[(size_t)row * NSLICE + sl] = sls;
    }
}

// ==== kernel 3: sum 4 partials per row, norm chain, write 4 replicated chunks ====
__global__ __launch_bounds__(256) void final_kernel(
        const uint2* __restrict__ pnum,
        const float* __restrict__ pmeta,
        const unsigned short* __restrict__ offs,
        float* __restrict__ out, int Bn) {
    const int row  = blockIdx.x * 4 + (threadIdx.x >> 6);
    const int lane = threadIdx.x & 63;
    const int h    = lane >> 5;
    const int p    = lane & 31;
    if (row >= Bn) return;

    const int cnt = (int)offs[(size_t)row * 5 + 4];
    float* orow = out + (size_t)row * (4 * Dc);
    if (cnt == 0) {
        if (lane < 32) {
            const float4 z4 = make_float4(0.f, 0.f, 0.f, 0.f);
            #pragma unroll
            for (int sc = 0; sc < 4; ++sc)
                *reinterpret_cast<float4*>(orow + sc * Dc + 4 * p) = z4;
        }
        return;
    }
    const float slam = pmeta[(size_t)row * NSLICE + 0] + pmeta[(size_t)row * NSLICE + 1]
                     + pmeta[(size_t)row * NSLICE + 2] + pmeta[(size_t)row * NSLICE + 3];

    float4 v = make_float4(0.f, 0.f, 0.f, 0.f);
    #pragma unroll
    for (int j = 0; j < 2; ++j) {
        const int s = h * 2 + j;
        const uint2 u = pnum[((size_t)row * NSLICE + s) * 32 + p];
        const float2 f0 = __half22float2(*reinterpret_cast<const __half2*>(&u.x));
        const float2 f1 = __half22float2(*reinterpret_cast<const __half2*>(&u.y));
        v.x += f0.x; v.y += f0.y; v.z += f1.x; v.w += f1.y;
    }
    v.x += __shfl_xor(v.x, 32);
    v.y += __shfl_xor(v.y, 32);
    v.z += __shfl_xor(v.z, 32);
    v.w += __shfl_xor(v.w, 32);

    const float cntf  = (float)cnt;
    const float rc    = 1.0f / cntf;
    const float dn    = (slam - cntf) * rc;             // mean(lam-1)
    const float denom = ((dn >= 0.f) ? 1.0f : -1.0f) * fmaxf(fabsf(dn), CLAMP_ABS_EPS);
    const float s1    = rc / denom;
    const float4 tm = make_float4(v.x * s1, v.y * s1, v.z * s1, v.w * s1);

    const float p2 = (lane < 32) ? (tm.x*tm.x + tm.y*tm.y + tm.z*tm.z + tm.w*tm.w) : 0.f;
    const float n2 = fmaxf(sqrtf(red64(p2)), MIN_NORM);
    const float xc = fminf(n2, 1.0f - ATANH_EPS);
    const float th = xc / (1.0f + sqrtf(fmaxf(1.0f - xc * xc, 0.f)));  // tanh(0.5*artanh)
    const float k1 = th / n2;
    const float4 mid = make_float4(tm.x * k1, tm.y * k1, tm.z * k1, tm.w * k1);

    const float q2 = (lane < 32) ? (mid.x*mid.x + mid.y*mid.y + mid.z*mid.z + mid.w*mid.w) : 0.f;
    const float nm  = fmaxf(sqrtf(red64(q2)), MIN_NORM);
    const float xc2 = fminf(nm, 1.0f - ATANH_EPS);
    const float f   = 0.5f * logf((1.0f + xc2) / (1.0f - xc2));        // artanh
    const float k2  = f / nm;

    if (lane < 32) {
        const float4 o = make_float4(mid.x * k2, mid.y * k2, mid.z * k2, mid.w * k2);
        #pragma unroll
        for (int sc = 0; sc < 4; ++sc)
            *reinterpret_cast<float4*>(orow + sc * Dc + 4 * p) = o;
    }
}

// ---- fallback (small ws): prep + single-kernel gather over w16 table ----
__global__ __launch_bounds__(256) void prep_kernel(
        const float* __restrict__ emb,
        __half* __restrict__ w16,
        float* __restrict__ lam, int V) {
    const int row  = blockIdx.x * 4 + (threadIdx.x >> 6);
    const int lane = threadIdx.x & 63;
    if (row >= V) return;
    const float2 z = *reinterpret_cast<const float2*>(emb + (size_t)row * Dc + lane * 2);
    const float p = red64(z.x * z.x + z.y * z.y);
    const float lamv = 2.0f / fmaxf(1.0f - p, MIN_NORM);
    if (lane == 0) lam[row] = lamv;
    *reinterpret_cast<__half2*>(w16 + (size_t)row * Dc + lane * 2) =
        __floats2half2_rn(lamv * z.x, lamv * z.y);
}

__global__ __launch_bounds__(256) void hyper_enc_kernel(
        const int* __restrict__ padded,
        const __half* __restrict__ w16,
        const float* __restrict__ lam,
        float* __restrict__ out) {
    const int b    = blockIdx.x;
    const int tid  = threadIdx.x;
    const int wave = tid >> 6;
    const int lane = tid & 63;
    const int half = lane >> 5;
    const int l32  = lane & 31;

    __shared__ int   sidx[Lc];
    __shared__ float s_num[8][Dc];
    __shared__ int   s_cnt;
    __shared__ float s_den[2];
    __shared__ float s_red[4];

    int   myidx = 0;
    float mylam = 0.f;
    if (tid < Lc) {
        myidx = padded[(size_t)b * Lc + tid];
        sidx[tid] = myidx;
        mylam = (myidx != PAD) ? lam[myidx] : 0.0f;
    }
    if (tid == 0) s_cnt = 0;
    __syncthreads();
    if (tid < Lc) {
        unsigned long long bal = __ballot(myidx != PAD);
        if (lane == 0) atomicAdd(&s_cnt, (int)__popcll(bal));
        float sl = red64(mylam);
        if (lane == 0) s_den[wave] = sl;
    }

    float4 snum = make_float4(0.f, 0.f, 0.f, 0.f);
    const int lbase = wave * 32 + half;
    __syncthreads();
    #pragma unroll
    for (int j = 0; j < 16; ++j) {
        const int idx = sidx[lbase + 2 * j];
        const uint2 r = *reinterpret_cast<const uint2*>(
            w16 + ((size_t)idx << 7) + (l32 << 2));
        const float2 f0 = __half22float2(*reinterpret_cast<const __half2*>(&r.x));
        const float2 f1 = __half22float2(*reinterpret_cast<const __half2*>(&r.y));
        snum.x += f0.x; snum.y += f0.y; snum.z += f1.x; snum.w += f1.y;
    }
    const int g = wave * 2 + half;
    *reinterpret_cast<float4*>(&s_num[g][l32 * 4]) = snum;
    __syncthreads();

    const int cnt = s_cnt;
    if (cnt == 0) {
        for (int i = tid; i < 4 * Dc; i += 256)
            out[(size_t)b * (4 * Dc) + i] = 0.f;
        return;
    }
    const float Sd = (s_den[0] + s_den[1]) - (float)cnt;

    float nom = 0.f;
    if (tid < Dc) {
        #pragma unroll
        for (int gg = 0; gg < 8; ++gg) nom += s_num[gg][tid];
    }
    float tm = 0.f;
    if (tid < Dc) {
        const float rc    = 1.0f / (float)cnt;
        const float dn    = Sd * rc;
        const float denom = ((dn >= 0.f) ? 1.0f : -1.0f) * fmaxf(fabsf(dn), CLAMP_ABS_EPS);
        tm = (nom * rc) / denom;
    }
    float p2 = red64(tm * tm);
    if (lane == 0) s_red[wave] = p2;
    __syncthreads();
    const float n2 = fmaxf(sqrtf(s_red[0] + s_red[1]), MIN_NORM);
    const float xc = fminf(n2, 1.0f - ATANH_EPS);
    const float t_half = xc / (1.0f + sqrtf(fmaxf(1.0f - xc * xc, 0.f)));
    const float mid = tm * (t_half / n2);
    __syncthreads();
    float q2 = red64(mid * mid);
    if (lane == 0) s_red[wave] = q2;
    __syncthreads();
    const float nm  = fmaxf(sqrtf(s_red[0] + s_red[1]), MIN_NORM);
    const float xc2 = fminf(nm, 1.0f - ATANH_EPS);
    const float f   = 0.5f * logf((1.0f + xc2) / (1.0f - xc2));
    if (tid < Dc) {
        const float o = mid * (f / nm);
        float* orow = out + (size_t)b * (4 * Dc);
        orow[0 * Dc + tid] = o;
        orow[1 * Dc + tid] = o;
        orow[2 * Dc + tid] = o;
        orow[3 * Dc + tid] = o;
    }
}

static inline size_t align256(size_t x) { return (x + 255) & ~(size_t)255; }

extern "C" void kernel_launch(void* const* d_in, const int* in_sizes, int n_in,
                              void* d_out, int out_size, void* d_ws, size_t ws_size,
                              hipStream_t stream) {
    const int*   padded = (const int*)d_in[0];
    const float* emb    = (const float*)d_in[1];
    float*       out    = (float*)d_out;
    const int Bn = in_sizes[0] / Lc;             // 8192
    const int V  = in_sizes[1] / Dc;             // 50000
    const int V4 = (V + NSLICE - 1) / NSLICE;
    const int nGrp = (Bn + 7) / 8;

    const size_t w16_b   = align256((size_t)(V + 1) * Dc * sizeof(__half));      // 12.8 MB
    const size_t lam_b   = align256((size_t)(V + 1) * sizeof(float));            // 200 KB
    const size_t cidx_b  = align256((size_t)Bn * Lc * sizeof(unsigned short));   // 2 MB
    const size_t offs_b  = align256((size_t)Bn * 5 * sizeof(unsigned short));
    const size_t pmeta_b = align256((size_t)Bn * NSLICE * sizeof(float));
    const size_t pnum_b  = align256((size_t)Bn * NSLICE * 32 * sizeof(uint2));   // 8.4 MB
    const size_t need    = w16_b + lam_b + cidx_b + offs_b + pmeta_b + pnum_b;

    if (ws_size >= need) {
        char* p = (char*)d_ws;
        __half*         w16   = (__half*)p;          p += w16_b;
        float*          lam   = (float*)p;           p += lam_b;
        unsigned short* cidx  = (unsigned short*)p;  p += cidx_b;
        unsigned short* offs  = (unsigned short*)p;  p += offs_b;
        float*          pmeta = (float*)p;           p += pmeta_b;
        uint2*          pnum  = (uint2*)p;
        const int nPrep   = (V + 1 + 3) / 4;
        const int nBucket = (Bn + 3) / 4;
        prep_bucket_kernel<<<nPrep + nBucket, 256, 0, stream>>>(
            emb, padded, w16, lam, cidx, offs, nPrep, V, Bn, V4);
        partial_kernel<<<NSLICE * nGrp, 256, 0, stream>>>(
            cidx, offs, lam, w16, pnum, pmeta, Bn, V);
        final_kernel<<<(Bn + 3) / 4, 256, 0, stream>>>(pnum, pmeta, offs, out, Bn);
    } else if (ws_size >= w16_b + lam_b) {
        __half* w16 = (__half*)d_ws;
        float*  lam = (float*)((char*)d_ws + w16_b);
        prep_kernel<<<(V + 3) / 4, 256, 0, stream>>>(emb, w16, lam, V);
        hyper_enc_kernel<<<Bn, 256, 0, stream>>>(padded, w16, lam, out);
    }
}

// Round 14
// 42.824 us; speedup vs baseline: 14.9682x; 1.0122x over previous
//
#include <hip/hip_runtime.h>
#include <hip/hip_fp16.h>
#include <math.h>

constexpr int PAD = 0;
constexpr int Lc = 128;   // sequence length
constexpr int Dc = 128;   // embedding dim
constexpr int NSLICE = 4; // vocab slices (XCD k caches slice k%4 under round-robin)
constexpr float MIN_NORM = 1e-15f;
constexpr float CLAMP_ABS_EPS = 1e-10f;
constexpr float ATANH_EPS = 1e-7f;

__device__ __forceinline__ float red64(float v) {
    v += __shfl_xor(v, 32);
    v += __shfl_xor(v, 16);
    v += __shfl_xor(v, 8);
    v += __shfl_xor(v, 4);
    v += __shfl_xor(v, 2);
    v += __shfl_xor(v, 1);
    return v;
}

__device__ __forceinline__ __half2 h2xadd(__half2 a, int m) {
    unsigned u = *reinterpret_cast<unsigned*>(&a);
    unsigned t = __shfl_xor(u, m);
    return __hadd2(a, *reinterpret_cast<__half2*>(&t));
}

// ==== kernel 1: prep (table) + bucket (indices) fused via disjoint block ranges ====
__global__ __launch_bounds__(256) void prep_bucket_kernel(
        const float* __restrict__ emb,
        const int* __restrict__ padded,
        __half* __restrict__ w16,            // [(V+1)][128], row V = zeros
        float* __restrict__ lam,             // [V+1], lam[V] = 0
        unsigned short* __restrict__ cidx,   // [Bn][128] slice-sorted token ids
        unsigned short* __restrict__ offs,   // [Bn][5] slice offsets, [4]=total cnt
        int nPrep, int V, int Bn, int V4) {
    const int blk  = blockIdx.x;
    const int tid  = threadIdx.x;
    const int lane = tid & 63;

    if (blk < nPrep) {
        // ---- prep: 4 table rows per block ----
        const int row = blk * 4 + (tid >> 6);
        if (row > V) return;
        if (row == V) {  // dummy zero row + lam[V]=0 (pad slots become free)
            if (lane == 0) lam[V] = 0.f;
            *reinterpret_cast<__half2*>(w16 + (size_t)V * Dc + lane * 2) =
                __floats2half2_rn(0.f, 0.f);
            return;
        }
        const float2 z = *reinterpret_cast<const float2*>(emb + (size_t)row * Dc + lane * 2);
        const float p = red64(z.x * z.x + z.y * z.y);
        const float lamv = 2.0f / fmaxf(1.0f - p, MIN_NORM);
        if (lane == 0) lam[row] = lamv;
        *reinterpret_cast<__half2*>(w16 + (size_t)row * Dc + lane * 2) =
            __floats2half2_rn(lamv * z.x, lamv * z.y);
    } else {
        // ---- bucket: 4 batch rows per block (independent of prep's outputs) ----
        const int row = (blk - nPrep) * 4 + (tid >> 6);
        if (row >= Bn) return;
        const int i0 = padded[(size_t)row * Lc + lane];
        const int i1 = padded[(size_t)row * Lc + 64 + lane];
        const bool p0 = (i0 != PAD);
        const bool p1 = (i1 != PAD);
        const int s0 = (i0 >= V4) + (i0 >= 2 * V4) + (i0 >= 3 * V4);
        const int s1 = (i1 >= V4) + (i1 >= 2 * V4) + (i1 >= 3 * V4);
        const unsigned long long lmask = (1ull << lane) - 1ull;
        int running = 0;
        #pragma unroll
        for (int s = 0; s < NSLICE; ++s) {
            const unsigned long long m0 = __ballot(p0 && (s0 == s));
            const unsigned long long m1 = __ballot(p1 && (s1 == s));
            const int c0 = __popcll(m0);
            if (lane == 0) offs[(size_t)row * 5 + s] = (unsigned short)running;
            if (p0 && (s0 == s))
                cidx[(size_t)row * Lc + running + __popcll(m0 & lmask)] = (unsigned short)i0;
            if (p1 && (s1 == s))
                cidx[(size_t)row * Lc + running + c0 + __popcll(m1 & lmask)] = (unsigned short)i1;
            running += c0 + __popcll(m1);
        }
        if (lane == 0) offs[(size_t)row * 5 + 4] = (unsigned short)running;
    }
}

// ==== kernel 2: pure slice-local gather-add; 16 tokens in flight; branch-free ====
__global__ __launch_bounds__(256) void partial_kernel(
        const unsigned short* __restrict__ cidx,
        const unsigned short* __restrict__ offs,
        const __half* __restrict__ w16,
        uint2* __restrict__ pnum,      // [Bn*4][32] packed half2x2 (128 dims)
        int Bn, int V) {
    const int sl   = blockIdx.x & (NSLICE - 1);  // round-robin -> stable XCD per slice
    const int r0   = (blockIdx.x >> 2) * 8;
    const int tid  = threadIdx.x;
    const int w    = tid >> 6;
    const int lane = tid & 63;
    const int q    = lane >> 4;
    const int l16  = lane & 15;

    __shared__ int sidx[4][2][Lc + 16];

    #pragma unroll
    for (int rr = 0; rr < 2; ++rr) {
        const int row = r0 + w * 2 + rr;
        if (row >= Bn) continue;
        const int off = offs[(size_t)row * 5 + sl];
        const int nxt = offs[(size_t)row * 5 + sl + 1];
        const int cnt = nxt - off;
        // stage slots; out-of-range -> dummy row V (w16 zeros)
        {
            const int s0i = off + lane;
            const int s1i = off + 64 + lane;
            const int t0 = (int)cidx[(size_t)row * Lc + (s0i < Lc ? s0i : Lc - 1)];
            const int t1 = (int)cidx[(size_t)row * Lc + (s1i < Lc ? s1i : Lc - 1)];
            sidx[w][rr][lane]      = (lane      < cnt) ? t0 : V;
            sidx[w][rr][64 + lane] = (64 + lane < cnt) ? t1 : V;
            if (lane < 16) sidx[w][rr][Lc + lane] = V;
        }

        const __half2 hz = __floats2half2_rn(0.f, 0.f);
        __half2 a0 = hz, a1 = hz, a2 = hz, a3 = hz;
        __half2 b0 = hz, b1 = hz, b2 = hz, b3 = hz;
        for (int k = q; k < cnt; k += 16) {
            const int i0 = sidx[w][rr][k];
            const int i1 = sidx[w][rr][k + 4];
            const int i2 = sidx[w][rr][k + 8];
            const int i3 = sidx[w][rr][k + 12];
            const uint4 v0 = *reinterpret_cast<const uint4*>(w16 + ((size_t)i0 << 7) + (l16 << 3));
            const uint4 v1 = *reinterpret_cast<const uint4*>(w16 + ((size_t)i1 << 7) + (l16 << 3));
            const uint4 v2 = *reinterpret_cast<const uint4*>(w16 + ((size_t)i2 << 7) + (l16 << 3));
            const uint4 v3 = *reinterpret_cast<const uint4*>(w16 + ((size_t)i3 << 7) + (l16 << 3));
            a0 = __hadd2(a0, *reinterpret_cast<const __half2*>(&v0.x));
            a1 = __hadd2(a1, *reinterpret_cast<const __half2*>(&v0.y));
            a2 = __hadd2(a2, *reinterpret_cast<const __half2*>(&v0.z));
            a3 = __hadd2(a3, *reinterpret_cast<const __half2*>(&v0.w));
            b0 = __hadd2(b0, *reinterpret_cast<const __half2*>(&v1.x));
            b1 = __hadd2(b1, *reinterpret_cast<const __half2*>(&v1.y));
            b2 = __hadd2(b2, *reinterpret_cast<const __half2*>(&v1.z));
            b3 = __hadd2(b3, *reinterpret_cast<const __half2*>(&v1.w));
            a0 = __hadd2(a0, *reinterpret_cast<const __half2*>(&v2.x));
            a1 = __hadd2(a1, *reinterpret_cast<const __half2*>(&v2.y));
            a2 = __hadd2(a2, *reinterpret_cast<const __half2*>(&v2.z));
            a3 = __hadd2(a3, *reinterpret_cast<const __half2*>(&v2.w));
            b0 = __hadd2(b0, *reinterpret_cast<const __half2*>(&v3.x));
            b1 = __hadd2(b1, *reinterpret_cast<const __half2*>(&v3.y));
            b2 = __hadd2(b2, *reinterpret_cast<const __half2*>(&v3.z));
            b3 = __hadd2(b3, *reinterpret_cast<const __half2*>(&v3.w));
        }
        a0 = __hadd2(a0, b0); a1 = __hadd2(a1, b1);
        a2 = __hadd2(a2, b2); a3 = __hadd2(a3, b3);
        // combine the 4 quarters (same dims, different tokens)
        a0 = h2xadd(a0, 16); a1 = h2xadd(a1, 16); a2 = h2xadd(a2, 16); a3 = h2xadd(a3, 16);
        a0 = h2xadd(a0, 32); a1 = h2xadd(a1, 32); a2 = h2xadd(a2, 32); a3 = h2xadd(a3, 32);
        if (lane < 16) {
            uint4 u;
            u.x = *reinterpret_cast<unsigned*>(&a0);
            u.y = *reinterpret_cast<unsigned*>(&a1);
            u.z = *reinterpret_cast<unsigned*>(&a2);
            u.w = *reinterpret_cast<unsigned*>(&a3);
            *reinterpret_cast<uint4*>(
                &pnum[((size_t)row * NSLICE + sl) * 32 + (l16 << 1)]) = u;
        }
    }
}

// ==== kernel 3: sum 4 partials per row + slam from L2-hot lam[], norm chain, output ====
__global__ __launch_bounds__(256) void final_kernel(
        const uint2* __restrict__ pnum,
        const unsigned short* __restrict__ cidx,
        const unsigned short* __restrict__ offs,
        const float* __restrict__ lam,
        float* __restrict__ out, int Bn, int V) {
    const int row  = blockIdx.x * 4 + (threadIdx.x >> 6);
    const int lane = threadIdx.x & 63;
    const int h    = lane >> 5;
    const int p    = lane & 31;
    if (row >= Bn) return;

    const int cnt = (int)offs[(size_t)row * 5 + 4];
    float* orow = out + (size_t)row * (4 * Dc);
    if (cnt == 0) {
        if (lane < 32) {
            const float4 z4 = make_float4(0.f, 0.f, 0.f, 0.f);
            #pragma unroll
            for (int sc = 0; sc < 4; ++sc)
                *reinterpret_cast<float4*>(orow + sc * Dc + 4 * p) = z4;
        }
        return;
    }
    // slam: gather lam over the row's compact token list (once per row; lam[V]=0)
    const int t0 = (lane      < cnt) ? (int)cidx[(size_t)row * Lc + lane]      : V;
    const int t1 = (64 + lane < cnt) ? (int)cidx[(size_t)row * Lc + 64 + lane] : V;
    const float slam = red64(lam[t0] + lam[t1]);

    float4 v = make_float4(0.f, 0.f, 0.f, 0.f);
    #pragma unroll
    for (int j = 0; j < 2; ++j) {
        const int s = h * 2 + j;
        const uint2 u = pnum[((size_t)row * NSLICE + s) * 32 + p];
        const float2 f0 = __half22float2(*reinterpret_cast<const __half2*>(&u.x));
        const float2 f1 = __half22float2(*reinterpret_cast<const __half2*>(&u.y));
        v.x += f0.x; v.y += f0.y; v.z += f1.x; v.w += f1.y;
    }
    v.x += __shfl_xor(v.x, 32);
    v.y += __shfl_xor(v.y, 32);
    v.z += __shfl_xor(v.z, 32);
    v.w += __shfl_xor(v.w, 32);

    const float cntf  = (float)cnt;
    const float rc    = 1.0f / cntf;
    const float dn    = (slam - cntf) * rc;             // mean(lam-1)
    const float denom = ((dn >= 0.f) ? 1.0f : -1.0f) * fmaxf(fabsf(dn), CLAMP_ABS_EPS);
    const float s1    = rc / denom;
    const float4 tm = make_float4(v.x * s1, v.y * s1, v.z * s1, v.w * s1);

    const float p2 = (lane < 32) ? (tm.x*tm.x + tm.y*tm.y + tm.z*tm.z + tm.w*tm.w) : 0.f;
    const float n2 = fmaxf(sqrtf(red64(p2)), MIN_NORM);
    const float xc = fminf(n2, 1.0f - ATANH_EPS);
    const float th = xc / (1.0f + sqrtf(fmaxf(1.0f - xc * xc, 0.f)));  // tanh(0.5*artanh)
    const float k1 = th / n2;
    const float4 mid = make_float4(tm.x * k1, tm.y * k1, tm.z * k1, tm.w * k1);

    const float q2 = (lane < 32) ? (mid.x*mid.x + mid.y*mid.y + mid.z*mid.z + mid.w*mid.w) : 0.f;
    const float nm  = fmaxf(sqrtf(red64(q2)), MIN_NORM);
    const float xc2 = fminf(nm, 1.0f - ATANH_EPS);
    const float f   = 0.5f * logf((1.0f + xc2) / (1.0f - xc2));        // artanh
    const float k2  = f / nm;

    if (lane < 32) {
        const float4 o = make_float4(mid.x * k2, mid.y * k2, mid.z * k2, mid.w * k2);
        #pragma unroll
        for (int sc = 0; sc < 4; ++sc)
            *reinterpret_cast<float4*>(orow + sc * Dc + 4 * p) = o;
    }
}

// ---- fallback (small ws): prep + single-kernel gather over w16 table ----
__global__ __launch_bounds__(256) void prep_kernel(
        const float* __restrict__ emb,
        __half* __restrict__ w16,
        float* __restrict__ lam, int V) {
    const int row  = blockIdx.x * 4 + (threadIdx.x >> 6);
    const int lane = threadIdx.x & 63;
    if (row >= V) return;
    const float2 z = *reinterpret_cast<const float2*>(emb + (size_t)row * Dc + lane * 2);
    const float p = red64(z.x * z.x + z.y * z.y);
    const float lamv = 2.0f / fmaxf(1.0f - p, MIN_NORM);
    if (lane == 0) lam[row] = lamv;
    *reinterpret_cast<__half2*>(w16 + (size_t)row * Dc + lane * 2) =
        __floats2half2_rn(lamv * z.x, lamv * z.y);
}

__global__ __launch_bounds__(256) void hyper_enc_kernel(
        const int* __restrict__ padded,
        const __half* __restrict__ w16,
        const float* __restrict__ lam,
        float* __restrict__ out) {
    const int b    = blockIdx.x;
    const int tid  = threadIdx.x;
    const int wave = tid >> 6;
    const int lane = tid & 63;
    const int half = lane >> 5;
    const int l32  = lane & 31;

    __shared__ int   sidx[Lc];
    __shared__ float s_num[8][Dc];
    __shared__ int   s_cnt;
    __shared__ float s_den[2];
    __shared__ float s_red[4];

    int   myidx = 0;
    float mylam = 0.f;
    if (tid < Lc) {
        myidx = padded[(size_t)b * Lc + tid];
        sidx[tid] = myidx;
        mylam = (myidx != PAD) ? lam[myidx] : 0.0f;
    }
    if (tid == 0) s_cnt = 0;
    __syncthreads();
    if (tid < Lc) {
        unsigned long long bal = __ballot(myidx != PAD);
        if (lane == 0) atomicAdd(&s_cnt, (int)__popcll(bal));
        float sl = red64(mylam);
        if (lane == 0) s_den[wave] = sl;
    }

    float4 snum = make_float4(0.f, 0.f, 0.f, 0.f);
    const int lbase = wave * 32 + half;
    __syncthreads();
    #pragma unroll
    for (int j = 0; j < 16; ++j) {
        const int idx = sidx[lbase + 2 * j];
        const uint2 r = *reinterpret_cast<const uint2*>(
            w16 + ((size_t)idx << 7) + (l32 << 2));
        const float2 f0 = __half22float2(*reinterpret_cast<const __half2*>(&r.x));
        const float2 f1 = __half22float2(*reinterpret_cast<const __half2*>(&r.y));
        snum.x += f0.x; snum.y += f0.y; snum.z += f1.x; snum.w += f1.y;
    }
    const int g = wave * 2 + half;
    *reinterpret_cast<float4*>(&s_num[g][l32 * 4]) = snum;
    __syncthreads();

    const int cnt = s_cnt;
    if (cnt == 0) {
        for (int i = tid; i < 4 * Dc; i += 256)
            out[(size_t)b * (4 * Dc) + i] = 0.f;
        return;
    }
    const float Sd = (s_den[0] + s_den[1]) - (float)cnt;

    float nom = 0.f;
    if (tid < Dc) {
        #pragma unroll
        for (int gg = 0; gg < 8; ++gg) nom += s_num[gg][tid];
    }
    float tm = 0.f;
    if (tid < Dc) {
        const float rc    = 1.0f / (float)cnt;
        const float dn    = Sd * rc;
        const float denom = ((dn >= 0.f) ? 1.0f : -1.0f) * fmaxf(fabsf(dn), CLAMP_ABS_EPS);
        tm = (nom * rc) / denom;
    }
    float p2 = red64(tm * tm);
    if (lane == 0) s_red[wave] = p2;
    __syncthreads();
    const float n2 = fmaxf(sqrtf(s_red[0] + s_red[1]), MIN_NORM);
    const float xc = fminf(n2, 1.0f - ATANH_EPS);
    const float t_half = xc / (1.0f + sqrtf(fmaxf(1.0f - xc * xc, 0.f)));
    const float mid = tm * (t_half / n2);
    __syncthreads();
    float q2 = red64(mid * mid);
    if (lane == 0) s_red[wave] = q2;
    __syncthreads();
    const float nm  = fmaxf(sqrtf(s_red[0] + s_red[1]), MIN_NORM);
    const float xc2 = fminf(nm, 1.0f - ATANH_EPS);
    const float f   = 0.5f * logf((1.0f + xc2) / (1.0f - xc2));
    if (tid < Dc) {
        const float o = mid * (f / nm);
        float* orow = out + (size_t)b * (4 * Dc);
        orow[0 * Dc + tid] = o;
        orow[1 * Dc + tid] = o;
        orow[2 * Dc + tid] = o;
        orow[3 * Dc + tid] = o;
    }
}

static inline size_t align256(size_t x) { return (x + 255) & ~(size_t)255; }

extern "C" void kernel_launch(void* const* d_in, const int* in_sizes, int n_in,
                              void* d_out, int out_size, void* d_ws, size_t ws_size,
                              hipStream_t stream) {
    const int*   padded = (const int*)d_in[0];
    const float* emb    = (const float*)d_in[1];
    float*       out    = (float*)d_out;
    const int Bn = in_sizes[0] / Lc;             // 8192
    const int V  = in_sizes[1] / Dc;             // 50000
    const int V4 = (V + NSLICE - 1) / NSLICE;
    const int nGrp = (Bn + 7) / 8;

    const size_t w16_b   = align256((size_t)(V + 1) * Dc * sizeof(__half));      // 12.8 MB
    const size_t lam_b   = align256((size_t)(V + 1) * sizeof(float));            // 200 KB
    const size_t cidx_b  = align256((size_t)Bn * Lc * sizeof(unsigned short));   // 2 MB
    const size_t offs_b  = align256((size_t)Bn * 5 * sizeof(unsigned short));
    const size_t pnum_b  = align256((size_t)Bn * NSLICE * 32 * sizeof(uint2));   // 8.4 MB
    const size_t need    = w16_b + lam_b + cidx_b + offs_b + pnum_b;

    if (ws_size >= need) {
        char* p = (char*)d_ws;
        __half*         w16   = (__half*)p;          p += w16_b;
        float*          lam   = (float*)p;           p += lam_b;
        unsigned short* cidx  = (unsigned short*)p;  p += cidx_b;
        unsigned short* offs  = (unsigned short*)p;  p += offs_b;
        uint2*          pnum  = (uint2*)p;
        const int nPrep   = (V + 1 + 3) / 4;
        const int nBucket = (Bn + 3) / 4;
        prep_bucket_kernel<<<nPrep + nBucket, 256, 0, stream>>>(
            emb, padded, w16, lam, cidx, offs, nPrep, V, Bn, V4);
        partial_kernel<<<NSLICE * nGrp, 256, 0, stream>>>(
            cidx, offs, w16, pnum, Bn, V);
        final_kernel<<<(Bn + 3) / 4, 256, 0, stream>>>(
            pnum, cidx, offs, lam, out, Bn, V);
    } else if (ws_size >= w16_b + lam_b) {
        __half* w16 = (__half*)d_ws;
        float*  lam = (float*)((char*)d_ws + w16_b);
        prep_kernel<<<(V + 3) / 4, 256, 0, stream>>>(emb, w16, lam, V);
        hyper_enc_kernel<<<Bn, 256, 0, stream>>>(padded, w16, lam, out);
    }
}